// Round 7
// baseline (6933.329 us; speedup 1.0000x reference)
//
#include <hip/hip_runtime.h>
#include <math.h>

#define TT 2048
#define EE 512
#define HDD 512
#define TAGS 32
#define STARTT 30
#define STOPP 31
#define NEGV -10000.0f
#define VCH 256
#define SENT 0xFFFFFFFFu   // hs sentinel: -NaN bit pattern, unreachable for finite h

// ---- xg[dir][t][n] = sum_k emb[sent[t]][k]*w_ih[n][k] + b[n], tile-flagged ----
__global__ __launch_bounds__(256) void k_xgemm(const int* __restrict__ sent,
        const float* __restrict__ emb,
        const float* __restrict__ wf, const float* __restrict__ wb,
        const float* __restrict__ bf, const float* __restrict__ bb,
        float* __restrict__ xg, int* __restrict__ xflag) {
    const int jj   = blockIdx.y >> 1;
    const int dir  = blockIdx.y & 1;
    const int tile = dir ? (31 - jj) : jj;     // urgent tiles first in dispatch
    const float* __restrict__ w    = dir ? wb : wf;
    const float* __restrict__ bias = dir ? bb : bf;
    const int tb = tile * 64;
    const int nb = blockIdx.x * 64;
    __shared__ float As[64][17];
    __shared__ float Bs[64][17];
    const int tid = threadIdx.x;
    const int lr = tid >> 2;
    const int lc = (tid & 3) * 4;
    const int ty = tid >> 4;
    const int tx = tid & 15;
    const int sidx = sent[tb + lr];            // fused embedding gather
    float acc[4][4] = {};
    for (int k0 = 0; k0 < EE; k0 += 16) {
        float4 av = *(const float4*)(emb + (size_t)sidx * EE + k0 + lc);
        float4 bv = *(const float4*)(w + (size_t)(nb + lr) * EE + k0 + lc);
        As[lr][lc+0] = av.x; As[lr][lc+1] = av.y; As[lr][lc+2] = av.z; As[lr][lc+3] = av.w;
        Bs[lr][lc+0] = bv.x; Bs[lr][lc+1] = bv.y; Bs[lr][lc+2] = bv.z; Bs[lr][lc+3] = bv.w;
        __syncthreads();
        #pragma unroll
        for (int kk = 0; kk < 16; ++kk) {
            float a[4], b[4];
            #pragma unroll
            for (int i = 0; i < 4; ++i) a[i] = As[ty*4+i][kk];
            #pragma unroll
            for (int j = 0; j < 4; ++j) b[j] = Bs[tx*4+j][kk];
            #pragma unroll
            for (int i = 0; i < 4; ++i)
                #pragma unroll
                for (int j = 0; j < 4; ++j)
                    acc[i][j] += a[i] * b[j];
        }
        __syncthreads();
    }
    #pragma unroll
    for (int i = 0; i < 4; ++i) {
        float4 o;
        o.x = acc[i][0] + bias[nb + tx*4 + 0];
        o.y = acc[i][1] + bias[nb + tx*4 + 1];
        o.z = acc[i][2] + bias[nb + tx*4 + 2];
        o.w = acc[i][3] + bias[nb + tx*4 + 3];
        *(float4*)(xg + ((size_t)dir*TT + tb + ty*4 + i) * 2048 + nb + tx*4) = o;
    }
    __syncthreads();
    if (tid == 0)
        __hip_atomic_fetch_add(&xflag[dir * 32 + tile], 1,
                               __ATOMIC_RELEASE, __HIP_MEMORY_SCOPE_AGENT);
}

__device__ __forceinline__ float fsig(float x) {
    return __builtin_amdgcn_rcpf(1.f + __expf(-x));
}
__device__ __forceinline__ float ftanh(float x) {
    return 2.f * __builtin_amdgcn_rcpf(1.f + __expf(-2.f * x)) - 1.f;
}

__device__ __forceinline__ void waitflag(const int* f) {
    while (__hip_atomic_load(f, __ATOMIC_ACQUIRE, __HIP_MEMORY_SCOPE_AGENT) < 32)
        __builtin_amdgcn_s_sleep(1);
}

// ---------------- bidirectional LSTM recurrence v4: DIRECTION-FUSED --------
// grid (32) x 256. Each wave owns 4 hidden units of BOTH directions
// (lane = unit*16+gate*4+seg as in R6). Step loop: b-phase then f-phase.
// The other direction's compute sits between each dir's h-store and the next
// poll of that h -> store->LLC-visible latency is hidden; steady-state polls
// hit on first try. Single LDS buffer per dir is race-free: read(s) <
// other-phase barrier(s) < write(s+1) in program order. Cross-WG dependency
// data-flagged via 0xFF sentinel; WG-cooperative dwordx2 polls (R6 scheme).
__global__ __launch_bounds__(256, 1) void k_lstm(const float* __restrict__ xg,
        const float* __restrict__ whhf, const float* __restrict__ whhb,
        const float* __restrict__ h0, const float* __restrict__ c0,
        float* __restrict__ hs, const int* __restrict__ xflag) {
    const int tid    = threadIdx.x;
    const int lane   = tid & 63;
    const int waveid = tid >> 6;
    const int unit   = lane >> 4;        // 0..3
    const int gate   = (lane >> 2) & 3;  // i,f,g,o
    const int seg    = lane & 3;         // k segment (128 floats)
    const int ubase  = (blockIdx.x * 4 + waveid) * 4;
    const int grow   = gate * HDD + ubase + unit;

    float4 wF[32], wB[32];
    {
        const float4* wp = (const float4*)(whhf + (size_t)grow * HDD + seg * 128);
        #pragma unroll
        for (int i = 0; i < 32; ++i) wF[i] = wp[i];
        const float4* wq = (const float4*)(whhb + (size_t)grow * HDD + seg * 128);
        #pragma unroll
        for (int i = 0; i < 32; ++i) wB[i] = wq[i];
    }

    // single buffer per dir, padded 4x132 (two barriers/step make it safe)
    __shared__ float hbF[528];
    __shared__ float hbB[528];

    float cF = c0[ubase + unit];
    float cB = c0[HDD + ubase + unit];

    const int g0 = 2 * tid;
    const int soff = (g0 >> 7) * 132 + (g0 & 127);
    hbF[soff]     = h0[g0];
    hbF[soff + 1] = h0[g0 + 1];
    hbB[soff]     = h0[HDD + g0];
    hbB[soff + 1] = h0[HDD + g0 + 1];

    const int* flagsF = xflag;
    const int* flagsB = xflag + 32;
    int ctF = 0, ctB = 31;
    waitflag(&flagsF[0]);
    waitflag(&flagsB[31]);
    float xvF = __uint_as_float(__hip_atomic_load(
        (const unsigned*)(xg + (size_t)0 * 2048 + grow),
        __ATOMIC_RELAXED, __HIP_MEMORY_SCOPE_AGENT));
    float xvB = __uint_as_float(__hip_atomic_load(
        (const unsigned*)(xg + ((size_t)TT + TT - 1) * 2048 + grow),
        __ATOMIC_RELAXED, __HIP_MEMORY_SCOPE_AGENT));

    for (int s = 0; s < TT; ++s) {
        const int tf = s;
        const int tb = TT - 1 - s;
        const float xf = xvF, xb = xvB;
        if (s + 1 < TT) {
            const int tfn = s + 1, tbn = TT - 2 - s;
            if ((tfn >> 6) != ctF) { waitflag(&flagsF[tfn >> 6]); ctF = tfn >> 6; }
            if ((tbn >> 6) != ctB) { waitflag(&flagsB[tbn >> 6]); ctB = tbn >> 6; }
            xvF = __uint_as_float(__hip_atomic_load(
                (const unsigned*)(xg + (size_t)tfn * 2048 + grow),
                __ATOMIC_RELAXED, __HIP_MEMORY_SCOPE_AGENT));
            xvB = __uint_as_float(__hip_atomic_load(
                (const unsigned*)(xg + ((size_t)TT + tbn) * 2048 + grow),
                __ATOMIC_RELAXED, __HIP_MEMORY_SCOPE_AGENT));
        }

        // ================= backward phase =================
        if (s > 0) {
            const unsigned long long* hsrc = (const unsigned long long*)
                (hs + ((size_t)TT + tb + 1) * HDD) + tid;
            unsigned long long vv = __hip_atomic_load(hsrc,
                    __ATOMIC_RELAXED, __HIP_MEMORY_SCOPE_AGENT);
            while ((unsigned)vv == SENT || (unsigned)(vv >> 32) == SENT)
                vv = __hip_atomic_load(hsrc,
                        __ATOMIC_RELAXED, __HIP_MEMORY_SCOPE_AGENT);
            hbB[soff]     = __uint_as_float((unsigned)vv);
            hbB[soff + 1] = __uint_as_float((unsigned)(vv >> 32));
        }
        __syncthreads();
        {
            const float4* hp = (const float4*)(hbB + seg * 132);
            float a0 = 0.f, a1 = 0.f, a2 = 0.f, a3 = 0.f;
            #pragma unroll
            for (int i = 0; i < 32; i += 4) {
                float4 h0v = hp[i], h1v = hp[i+1], h2v = hp[i+2], h3v = hp[i+3];
                a0 += wB[i  ].x*h0v.x + wB[i  ].y*h0v.y + wB[i  ].z*h0v.z + wB[i  ].w*h0v.w;
                a1 += wB[i+1].x*h1v.x + wB[i+1].y*h1v.y + wB[i+1].z*h1v.z + wB[i+1].w*h1v.w;
                a2 += wB[i+2].x*h2v.x + wB[i+2].y*h2v.y + wB[i+2].z*h2v.z + wB[i+2].w*h2v.w;
                a3 += wB[i+3].x*h3v.x + wB[i+3].y*h3v.y + wB[i+3].z*h3v.z + wB[i+3].w*h3v.w;
            }
            float acc = (a0 + a1) + (a2 + a3);
            acc += __shfl_xor(acc, 1);
            acc += __shfl_xor(acc, 2);
            acc += xb;
            const int base = lane & ~15;
            const float iv = __shfl(acc, base + 0);
            const float fv = __shfl(acc, base + 4);
            const float gv = __shfl(acc, base + 8);
            const float ov = __shfl(acc, base + 12);
            cB = fsig(fv) * cB + fsig(iv) * ftanh(gv);
            const float h = fsig(ov) * ftanh(cB);
            if ((lane & 15) == 0)
                __hip_atomic_store(&hs[((size_t)TT + tb) * HDD + ubase + unit], h,
                                   __ATOMIC_RELAXED, __HIP_MEMORY_SCOPE_AGENT);
        }

        // ================= forward phase =================
        if (s > 0) {
            const unsigned long long* hsrc = (const unsigned long long*)
                (hs + (size_t)(tf - 1) * HDD) + tid;
            unsigned long long vv = __hip_atomic_load(hsrc,
                    __ATOMIC_RELAXED, __HIP_MEMORY_SCOPE_AGENT);
            while ((unsigned)vv == SENT || (unsigned)(vv >> 32) == SENT)
                vv = __hip_atomic_load(hsrc,
                        __ATOMIC_RELAXED, __HIP_MEMORY_SCOPE_AGENT);
            hbF[soff]     = __uint_as_float((unsigned)vv);
            hbF[soff + 1] = __uint_as_float((unsigned)(vv >> 32));
        }
        __syncthreads();
        {
            const float4* hp = (const float4*)(hbF + seg * 132);
            float a0 = 0.f, a1 = 0.f, a2 = 0.f, a3 = 0.f;
            #pragma unroll
            for (int i = 0; i < 32; i += 4) {
                float4 h0v = hp[i], h1v = hp[i+1], h2v = hp[i+2], h3v = hp[i+3];
                a0 += wF[i  ].x*h0v.x + wF[i  ].y*h0v.y + wF[i  ].z*h0v.z + wF[i  ].w*h0v.w;
                a1 += wF[i+1].x*h1v.x + wF[i+1].y*h1v.y + wF[i+1].z*h1v.z + wF[i+1].w*h1v.w;
                a2 += wF[i+2].x*h2v.x + wF[i+2].y*h2v.y + wF[i+2].z*h2v.z + wF[i+2].w*h2v.w;
                a3 += wF[i+3].x*h3v.x + wF[i+3].y*h3v.y + wF[i+3].z*h3v.z + wF[i+3].w*h3v.w;
            }
            float acc = (a0 + a1) + (a2 + a3);
            acc += __shfl_xor(acc, 1);
            acc += __shfl_xor(acc, 2);
            acc += xf;
            const int base = lane & ~15;
            const float iv = __shfl(acc, base + 0);
            const float fv = __shfl(acc, base + 4);
            const float gv = __shfl(acc, base + 8);
            const float ov = __shfl(acc, base + 12);
            cF = fsig(fv) * cF + fsig(iv) * ftanh(gv);
            const float h = fsig(ov) * ftanh(cF);
            if ((lane & 15) == 0)
                __hip_atomic_store(&hs[(size_t)tf * HDD + ubase + unit], h,
                                   __ATOMIC_RELAXED, __HIP_MEMORY_SCOPE_AGENT);
        }
    }
}

// ------- feats[t][tag] = sum_k concat(hf,hb)[t][k]*W_out[tag][k] + b_out -----
__global__ __launch_bounds__(256) void k_feats(const float* __restrict__ hs,
        const float* __restrict__ Wout, const float* __restrict__ bout,
        float* __restrict__ feats) {
    const int t = blockIdx.x;
    const int tid = threadIdx.x;
    const int tag = tid >> 3;
    const int chunk = tid & 7;
    const float* __restrict__ hrow = (chunk < 4)
        ? hs + (size_t)t * HDD
        : hs + ((size_t)TT + t) * HDD - 512;
    float acc = 0.f;
    const float4* wp = (const float4*)(Wout + (size_t)tag * 1024 + chunk * 128);
    const float4* hp = (const float4*)(hrow + chunk * 128);
    #pragma unroll
    for (int i = 0; i < 32; ++i) {
        float4 wv = wp[i];
        float4 hv = hp[i];
        acc += wv.x*hv.x + wv.y*hv.y + wv.z*hv.z + wv.w*hv.w;
    }
    __shared__ float red[TAGS][9];
    red[tag][chunk] = acc;
    __syncthreads();
    if (tid < TAGS) {
        float s = bout[tid];
        #pragma unroll
        for (int c = 0; c < 8; ++c) s += red[tid][c];
        feats[(size_t)t * TAGS + tid] = s;
    }
}

// ------- Viterbi: single wave; bp in LDS; 2-way prev split per tag ---------
__global__ __launch_bounds__(64) void k_viterbi(const float* __restrict__ feats,
        const float* __restrict__ trans, float* __restrict__ out) {
    const int lane = threadIdx.x;
    const int n  = lane & 31;   // next tag
    const int ph = lane >> 5;   // prev half
    __shared__ float fvs[TAGS];
    __shared__ unsigned char bp[TT][TAGS];            // 64 KiB backtrack
    __shared__ __align__(16) float fbuf[VCH * TAGS];  // 32 KiB feats chunk
    float tr[16];
    #pragma unroll
    for (int p = 0; p < 16; ++p) tr[p] = trans[n * TAGS + ph * 16 + p];
    if (lane < TAGS) fvs[lane] = (lane == STARTT) ? 0.f : NEGV;
    __syncthreads();
    for (int c0 = 0; c0 < TT; c0 += VCH) {
        const float4* src = (const float4*)(feats + (size_t)c0 * TAGS);
        float4* dst = (float4*)fbuf;
        for (int i = lane; i < VCH * TAGS / 4; i += 64) dst[i] = src[i];
        __syncthreads();
        for (int lt = 0; lt < VCH; ++lt) {
            const int t = c0 + lt;
            float bv = fvs[ph * 16] + tr[0];
            int bi = ph * 16;
            #pragma unroll
            for (int p = 1; p < 16; ++p) {
                const float cand = fvs[ph * 16 + p] + tr[p];
                if (cand > bv) { bv = cand; bi = ph * 16 + p; }
            }
            const float obv = __shfl_xor(bv, 32);
            const int   obi = __shfl_xor(bi, 32);
            if (obv > bv || (obv == bv && obi < bi)) { bv = obv; bi = obi; }
            const float nf = bv + fbuf[lt * TAGS + n];
            if (ph == 0) bp[t][n] = (unsigned char)bi;
            __syncthreads();
            if (ph == 0) fvs[n] = nf;
            __syncthreads();
        }
    }
    if (lane < TAGS) fvs[lane] += trans[STOPP * TAGS + lane];
    __syncthreads();
    if (lane == 0) {
        float bs = fvs[0]; int best = 0;
        for (int i = 1; i < TAGS; ++i)
            if (fvs[i] > bs) { bs = fvs[i]; best = i; }
        out[0] = bs;
        int tag = best;
        for (int t = TT - 1; t >= 0; --t) {
            out[1 + t] = (float)tag;
            tag = bp[t][tag];
        }
    }
}

extern "C" void kernel_launch(void* const* d_in, const int* in_sizes, int n_in,
                              void* d_out, int out_size, void* d_ws, size_t ws_size,
                              hipStream_t stream) {
    const int*   sent  = (const int*)  d_in[0];
    const float* emb   = (const float*)d_in[1];
    const float* wihf  = (const float*)d_in[2];
    const float* whhf  = (const float*)d_in[3];
    const float* bfv   = (const float*)d_in[4];
    const float* wihb  = (const float*)d_in[5];
    const float* whhb  = (const float*)d_in[6];
    const float* bbv   = (const float*)d_in[7];
    const float* Wout  = (const float*)d_in[8];
    const float* bout  = (const float*)d_in[9];
    const float* trans = (const float*)d_in[10];
    const float* h0    = (const float*)d_in[11];
    const float* c0    = (const float*)d_in[12];
    float* out = (float*)d_out;

    char* ws = (char*)d_ws;
    float* xg    = (float*)(ws + ((size_t)4  << 20));             // 32 MiB [2][T][2048]
    float* hs    = (float*)(ws + ((size_t)36 << 20));             //  8 MiB [2][T][512]
    float* feats = (float*)(ws + ((size_t)44 << 20));             // 256 KiB
    int* xflag   = (int*)  (ws + ((size_t)44 << 20) + (320u << 10)); // 64 ints

    hipMemsetAsync(hs, 0xFF, (size_t)2 * TT * HDD * sizeof(float), stream);
    hipMemsetAsync(xflag, 0, 64 * sizeof(int), stream);
    k_xgemm  <<<dim3(32, 64), 256, 0, stream>>>(sent, emb, wihf, wihb, bfv, bbv,
                                                xg, xflag);
    k_lstm   <<<dim3(32), 256, 0, stream>>>(xg, whhf, whhb, h0, c0, hs, xflag);
    k_feats  <<<TT, 256, 0, stream>>>(hs, Wout, bout, feats);
    k_viterbi<<<1, 64, 0, stream>>>(feats, trans, out);
}

// Round 8
// 4445.983 us; speedup vs baseline: 1.5595x; 1.5595x over previous
//
#include <hip/hip_runtime.h>
#include <math.h>

#define TT 2048
#define EE 512
#define HDD 512
#define TAGS 32
#define STARTT 30
#define STOPP 31
#define NEGV -10000.0f
#define VCH 256
#define SENT 0xFFFFFFFFu   // hs sentinel: -NaN bit pattern, unreachable for finite h

__device__ __forceinline__ float fsig(float x) {
    return __builtin_amdgcn_rcpf(1.f + __expf(-x));
}
__device__ __forceinline__ float ftanh(float x) {
    return 2.f * __builtin_amdgcn_rcpf(1.f + __expf(-2.f * x)) - 1.f;
}
__device__ __forceinline__ void waitflag(const int* f) {
    while (__hip_atomic_load(f, __ATOMIC_ACQUIRE, __HIP_MEMORY_SCOPE_AGENT) < 32)
        __builtin_amdgcn_s_sleep(1);
}

// ================= mega-kernel: gemm-role + lstm-role, truly concurrent =====
// blocks 0..63   : LSTM WGs (R6 k_lstm verbatim; wg = bid&31, dir = bid>>5).
//                  Dispatched first -> co-resident before gemm blocks.
// blocks 64..2111: xgemm tiles (R6 k_xgemm verbatim), urgent-first ordering;
//                  release-add xflag after tile store (release = L2 writeback,
//                  so lstm's acquire+atomic xg loads see fresh data).
// Single launch => the ~300-450us of serial xgemm time now overlaps the
// latency-bound lstm chain. Deadlock-free: gemm blocks never wait.
__global__ __launch_bounds__(256, 2) void k_main(
        const int* __restrict__ sent, const float* __restrict__ emb,
        const float* __restrict__ wihf, const float* __restrict__ whhf,
        const float* __restrict__ bfv,
        const float* __restrict__ wihb, const float* __restrict__ whhb,
        const float* __restrict__ bbv,
        const float* __restrict__ h0, const float* __restrict__ c0,
        float* __restrict__ xg, float* __restrict__ hs,
        int* __restrict__ xflag) {
    const int tid = threadIdx.x;

    if (blockIdx.x >= 64) {
        // ============================ GEMM role ============================
        const int gid  = blockIdx.x - 64;
        const int gy   = gid >> 5;
        const int jj   = gy >> 1;
        const int dir  = gy & 1;
        const int tile = dir ? (31 - jj) : jj;     // urgent tiles first
        const float* __restrict__ w    = dir ? wihb : wihf;
        const float* __restrict__ bias = dir ? bbv : bfv;
        const int tb = tile * 64;
        const int nb = (gid & 31) * 64;
        __shared__ float As[64][17];
        __shared__ float Bs[64][17];
        const int lr = tid >> 2;
        const int lc = (tid & 3) * 4;
        const int ty = tid >> 4;
        const int tx = tid & 15;
        const int sidx = sent[tb + lr];            // fused embedding gather
        float acc[4][4] = {};
        for (int k0 = 0; k0 < EE; k0 += 16) {
            float4 av = *(const float4*)(emb + (size_t)sidx * EE + k0 + lc);
            float4 bv = *(const float4*)(w + (size_t)(nb + lr) * EE + k0 + lc);
            As[lr][lc+0] = av.x; As[lr][lc+1] = av.y; As[lr][lc+2] = av.z; As[lr][lc+3] = av.w;
            Bs[lr][lc+0] = bv.x; Bs[lr][lc+1] = bv.y; Bs[lr][lc+2] = bv.z; Bs[lr][lc+3] = bv.w;
            __syncthreads();
            #pragma unroll
            for (int kk = 0; kk < 16; ++kk) {
                float a[4], b[4];
                #pragma unroll
                for (int i = 0; i < 4; ++i) a[i] = As[ty*4+i][kk];
                #pragma unroll
                for (int j = 0; j < 4; ++j) b[j] = Bs[tx*4+j][kk];
                #pragma unroll
                for (int i = 0; i < 4; ++i)
                    #pragma unroll
                    for (int j = 0; j < 4; ++j)
                        acc[i][j] += a[i] * b[j];
            }
            __syncthreads();
        }
        #pragma unroll
        for (int i = 0; i < 4; ++i) {
            float4 o;
            o.x = acc[i][0] + bias[nb + tx*4 + 0];
            o.y = acc[i][1] + bias[nb + tx*4 + 1];
            o.z = acc[i][2] + bias[nb + tx*4 + 2];
            o.w = acc[i][3] + bias[nb + tx*4 + 3];
            *(float4*)(xg + ((size_t)dir*TT + tb + ty*4 + i) * 2048 + nb + tx*4) = o;
        }
        __syncthreads();
        if (tid == 0)
            __hip_atomic_fetch_add(&xflag[dir * 32 + tile], 1,
                                   __ATOMIC_RELEASE, __HIP_MEMORY_SCOPE_AGENT);
        return;
    }

    // ============================ LSTM role (R6 verbatim) ==================
    const int wg  = blockIdx.x & 31;
    const int dir = blockIdx.x >> 5;
    const float* __restrict__ whh = dir ? whhb : whhf;
    const int lane   = tid & 63;
    const int waveid = tid >> 6;
    const int unit   = lane >> 4;        // 0..3
    const int gate   = (lane >> 2) & 3;  // i,f,g,o
    const int seg    = lane & 3;         // k segment (128 floats)
    const int ubase  = (wg * 4 + waveid) * 4;
    const int grow   = gate * HDD + ubase + unit;

    float4 w[32];
    {
        const float4* wp = (const float4*)(whh + (size_t)grow * HDD + seg * 128);
        #pragma unroll
        for (int i = 0; i < 32; ++i) w[i] = wp[i];
    }

    __shared__ float hbuf[2][528];   // double-buffered, padded 4x132

    float c = c0[dir * HDD + ubase + unit];

    const int* flags = xflag + dir * 32;
    const int t0 = dir ? (TT - 1) : 0;
    int curtile = t0 >> 6;
    waitflag(&flags[curtile]);
    float xvn = __uint_as_float(__hip_atomic_load(
        (const unsigned*)(xg + ((size_t)dir * TT + t0) * 2048 + grow),
        __ATOMIC_RELAXED, __HIP_MEMORY_SCOPE_AGENT));

    // stage step 0's h (from h0) into buf 0: 2 consecutive floats per lane
    const int g0 = 2 * tid;
    const int soff = (g0 >> 7) * 132 + (g0 & 127);
    hbuf[0][soff]     = h0[dir * HDD + g0];
    hbuf[0][soff + 1] = h0[dir * HDD + g0 + 1];

    for (int s = 0; s < TT; ++s) {
        const int t = dir ? (TT - 1 - s) : s;
        const float xv = xvn;
        if (s + 1 < TT) {
            const int tn = dir ? (TT - 2 - s) : (s + 1);
            const int tilen = tn >> 6;
            if (tilen != curtile) { waitflag(&flags[tilen]); curtile = tilen; }
            xvn = __uint_as_float(__hip_atomic_load(
                (const unsigned*)(xg + ((size_t)dir * TT + tn) * 2048 + grow),
                __ATOMIC_RELAXED, __HIP_MEMORY_SCOPE_AGENT));
        }

        float* hb = hbuf[s & 1];
        if (s > 0) {
            const int tprev = dir ? (t + 1) : (t - 1);
            const unsigned long long* hsrc = (const unsigned long long*)
                (hs + ((size_t)dir * TT + tprev) * HDD) + tid;
            unsigned long long vv = __hip_atomic_load(hsrc,
                    __ATOMIC_RELAXED, __HIP_MEMORY_SCOPE_AGENT);
            while ((unsigned)vv == SENT || (unsigned)(vv >> 32) == SENT)
                vv = __hip_atomic_load(hsrc,
                        __ATOMIC_RELAXED, __HIP_MEMORY_SCOPE_AGENT);
            hb[soff]     = __uint_as_float((unsigned)vv);
            hb[soff + 1] = __uint_as_float((unsigned)(vv >> 32));
        }
        __syncthreads();

        const float4* hp = (const float4*)(hb + seg * 132);
        float a0 = 0.f, a1 = 0.f, a2 = 0.f, a3 = 0.f;
        #pragma unroll
        for (int i = 0; i < 32; i += 4) {
            float4 h0v = hp[i], h1v = hp[i+1], h2v = hp[i+2], h3v = hp[i+3];
            a0 += w[i  ].x*h0v.x + w[i  ].y*h0v.y + w[i  ].z*h0v.z + w[i  ].w*h0v.w;
            a1 += w[i+1].x*h1v.x + w[i+1].y*h1v.y + w[i+1].z*h1v.z + w[i+1].w*h1v.w;
            a2 += w[i+2].x*h2v.x + w[i+2].y*h2v.y + w[i+2].z*h2v.z + w[i+2].w*h2v.w;
            a3 += w[i+3].x*h3v.x + w[i+3].y*h3v.y + w[i+3].z*h3v.z + w[i+3].w*h3v.w;
        }
        float acc = (a0 + a1) + (a2 + a3);
        acc += __shfl_xor(acc, 1);
        acc += __shfl_xor(acc, 2);
        acc += xv;

        const int base = lane & ~15;
        const float iv = __shfl(acc, base + 0);
        const float fv = __shfl(acc, base + 4);
        const float gv = __shfl(acc, base + 8);
        const float ov = __shfl(acc, base + 12);
        c = fsig(fv) * c + fsig(iv) * ftanh(gv);
        const float h = fsig(ov) * ftanh(c);

        if ((lane & 15) == 0)
            __hip_atomic_store(&hs[((size_t)dir * TT + t) * HDD + ubase + unit], h,
                               __ATOMIC_RELAXED, __HIP_MEMORY_SCOPE_AGENT);
    }
}

// ------- feats[t][tag] = sum_k concat(hf,hb)[t][k]*W_out[tag][k] + b_out -----
__global__ __launch_bounds__(256) void k_feats(const float* __restrict__ hs,
        const float* __restrict__ Wout, const float* __restrict__ bout,
        float* __restrict__ feats) {
    const int t = blockIdx.x;
    const int tid = threadIdx.x;
    const int tag = tid >> 3;
    const int chunk = tid & 7;
    const float* __restrict__ hrow = (chunk < 4)
        ? hs + (size_t)t * HDD
        : hs + ((size_t)TT + t) * HDD - 512;
    float acc = 0.f;
    const float4* wp = (const float4*)(Wout + (size_t)tag * 1024 + chunk * 128);
    const float4* hp = (const float4*)(hrow + chunk * 128);
    #pragma unroll
    for (int i = 0; i < 32; ++i) {
        float4 wv = wp[i];
        float4 hv = hp[i];
        acc += wv.x*hv.x + wv.y*hv.y + wv.z*hv.z + wv.w*hv.w;
    }
    __shared__ float red[TAGS][9];
    red[tag][chunk] = acc;
    __syncthreads();
    if (tid < TAGS) {
        float s = bout[tid];
        #pragma unroll
        for (int c = 0; c < 8; ++c) s += red[tid][c];
        feats[(size_t)t * TAGS + tid] = s;
    }
}

// ------- Viterbi: single wave; bp in LDS; 2-way prev split per tag ---------
__global__ __launch_bounds__(64) void k_viterbi(const float* __restrict__ feats,
        const float* __restrict__ trans, float* __restrict__ out) {
    const int lane = threadIdx.x;
    const int n  = lane & 31;   // next tag
    const int ph = lane >> 5;   // prev half
    __shared__ float fvs[TAGS];
    __shared__ unsigned char bp[TT][TAGS];            // 64 KiB backtrack
    __shared__ __align__(16) float fbuf[VCH * TAGS];  // 32 KiB feats chunk
    float tr[16];
    #pragma unroll
    for (int p = 0; p < 16; ++p) tr[p] = trans[n * TAGS + ph * 16 + p];
    if (lane < TAGS) fvs[lane] = (lane == STARTT) ? 0.f : NEGV;
    __syncthreads();
    for (int c0 = 0; c0 < TT; c0 += VCH) {
        const float4* src = (const float4*)(feats + (size_t)c0 * TAGS);
        float4* dst = (float4*)fbuf;
        for (int i = lane; i < VCH * TAGS / 4; i += 64) dst[i] = src[i];
        __syncthreads();
        for (int lt = 0; lt < VCH; ++lt) {
            const int t = c0 + lt;
            float bv = fvs[ph * 16] + tr[0];
            int bi = ph * 16;
            #pragma unroll
            for (int p = 1; p < 16; ++p) {
                const float cand = fvs[ph * 16 + p] + tr[p];
                if (cand > bv) { bv = cand; bi = ph * 16 + p; }
            }
            const float obv = __shfl_xor(bv, 32);
            const int   obi = __shfl_xor(bi, 32);
            if (obv > bv || (obv == bv && obi < bi)) { bv = obv; bi = obi; }
            const float nf = bv + fbuf[lt * TAGS + n];
            if (ph == 0) bp[t][n] = (unsigned char)bi;
            __syncthreads();
            if (ph == 0) fvs[n] = nf;
            __syncthreads();
        }
    }
    if (lane < TAGS) fvs[lane] += trans[STOPP * TAGS + lane];
    __syncthreads();
    if (lane == 0) {
        float bs = fvs[0]; int best = 0;
        for (int i = 1; i < TAGS; ++i)
            if (fvs[i] > bs) { bs = fvs[i]; best = i; }
        out[0] = bs;
        int tag = best;
        for (int t = TT - 1; t >= 0; --t) {
            out[1 + t] = (float)tag;
            tag = bp[t][tag];
        }
    }
}

extern "C" void kernel_launch(void* const* d_in, const int* in_sizes, int n_in,
                              void* d_out, int out_size, void* d_ws, size_t ws_size,
                              hipStream_t stream) {
    const int*   sent  = (const int*)  d_in[0];
    const float* emb   = (const float*)d_in[1];
    const float* wihf  = (const float*)d_in[2];
    const float* whhf  = (const float*)d_in[3];
    const float* bfv   = (const float*)d_in[4];
    const float* wihb  = (const float*)d_in[5];
    const float* whhb  = (const float*)d_in[6];
    const float* bbv   = (const float*)d_in[7];
    const float* Wout  = (const float*)d_in[8];
    const float* bout  = (const float*)d_in[9];
    const float* trans = (const float*)d_in[10];
    const float* h0    = (const float*)d_in[11];
    const float* c0    = (const float*)d_in[12];
    float* out = (float*)d_out;

    char* ws = (char*)d_ws;
    float* xg    = (float*)(ws + ((size_t)4  << 20));             // 32 MiB [2][T][2048]
    float* hs    = (float*)(ws + ((size_t)36 << 20));             //  8 MiB [2][T][512]
    float* feats = (float*)(ws + ((size_t)44 << 20));             // 256 KiB
    int* xflag   = (int*)  (ws + ((size_t)44 << 20) + (320u << 10)); // 64 ints

    hipMemsetAsync(hs, 0xFF, (size_t)2 * TT * HDD * sizeof(float), stream);
    hipMemsetAsync(xflag, 0, 64 * sizeof(int), stream);
    k_main   <<<dim3(64 + 2048), 256, 0, stream>>>(sent, emb, wihf, whhf, bfv,
                                                   wihb, whhb, bbv, h0, c0,
                                                   xg, hs, xflag);
    k_feats  <<<TT, 256, 0, stream>>>(hs, Wout, bout, feats);
    k_viterbi<<<1, 64, 0, stream>>>(feats, trans, out);
}